// Round 5
// baseline (4802.319 us; speedup 1.0000x reference)
//
#include <hip/hip_runtime.h>

#define D 256
#define BSHIFT 6
#define BSIZE 64          // nodes per bucket
#define KMAX 2048         // max buckets (LDS arrays)
#define NB_P 256          // partition blocks

using bf16x8 = __attribute__((ext_vector_type(8))) short;
using f32x4  = __attribute__((ext_vector_type(4))) float;

__device__ inline float bf_lo(unsigned int u) {
    return __builtin_bit_cast(float, u << 16);
}
__device__ inline float bf_hi(unsigned int u) {
    return __builtin_bit_cast(float, u & 0xffff0000u);
}
__device__ inline unsigned short f2bf(float f) {
    unsigned int x = __builtin_bit_cast(unsigned int, f);
    unsigned int r = (x + 0x7fffu + ((x >> 16) & 1u)) >> 16;   // RNE
    return (unsigned short)r;
}

// ---------------------------------------------------------------------------
// Converters
// ---------------------------------------------------------------------------
__global__ __launch_bounds__(256) void conv_feature_kernel(
    const float* __restrict__ f, unsigned short* __restrict__ o, long n8)
{
    long i = (long)blockIdx.x * blockDim.x + threadIdx.x;   // 8 floats each
    if (i >= n8) return;
    const float4* p = reinterpret_cast<const float4*>(f + i * 8);
    float4 v0 = p[0], v1 = p[1];
    uint4 r;
    r.x = (unsigned int)f2bf(v0.x) | ((unsigned int)f2bf(v0.y) << 16);
    r.y = (unsigned int)f2bf(v0.z) | ((unsigned int)f2bf(v0.w) << 16);
    r.z = (unsigned int)f2bf(v1.x) | ((unsigned int)f2bf(v1.y) << 16);
    r.w = (unsigned int)f2bf(v1.z) | ((unsigned int)f2bf(v1.w) << 16);
    *reinterpret_cast<uint4*>(o + i * 8) = r;
}

// Wt[n][k] = bf16(W[k][n])
__global__ __launch_bounds__(256) void conv_w_kernel(
    const float* __restrict__ W, unsigned short* __restrict__ Wt)
{
    int i = blockIdx.x * blockDim.x + threadIdx.x;   // 4 k's each
    if (i >= D * D / 4) return;
    int n  = i >> 6;
    int k0 = (i & 63) * 4;
    float a = W[(size_t)(k0 + 0) * D + n];
    float b = W[(size_t)(k0 + 1) * D + n];
    float c = W[(size_t)(k0 + 2) * D + n];
    float d = W[(size_t)(k0 + 3) * D + n];
    uint2 r;
    r.x = (unsigned int)f2bf(a) | ((unsigned int)f2bf(b) << 16);
    r.y = (unsigned int)f2bf(c) | ((unsigned int)f2bf(d) << 16);
    *reinterpret_cast<uint2*>(Wt + (size_t)n * D + k0) = r;
}

// ---------------------------------------------------------------------------
// Bucket partition: per-block LDS histograms -> bucket totals -> base scan ->
// scatter with global atomic claims (no within-bucket ordering needed).
// ---------------------------------------------------------------------------
__global__ __launch_bounds__(256) void histA_kernel(
    const int* __restrict__ dst, int* __restrict__ blockHist,
    int E, int K, int chunk)
{
    __shared__ int h[KMAX];
    const int b = blockIdx.x, t = threadIdx.x;
    for (int i = t; i < K; i += 256) h[i] = 0;
    __syncthreads();
    const int beg = b * chunk;
    const int end = min(beg + chunk, E);
    for (int i = beg + t; i < end; i += 256)
        atomicAdd(&h[dst[i] >> BSHIFT], 1);
    __syncthreads();
    for (int i = t; i < K; i += 256)
        blockHist[(size_t)b * K + i] = h[i];
}

// segment sums over blocks: segsum[seg][k] = sum_{b in seg of 64} blockHist[b][k]
__global__ __launch_bounds__(256) void colsumA_kernel(
    const int* __restrict__ blockHist, int* __restrict__ segsum, int K)
{
    int k = blockIdx.x * 256 + threadIdx.x;
    int seg = blockIdx.y;
    if (k >= K) return;
    int s = 0;
    const int b0 = seg * 64;
    for (int b = b0; b < b0 + 64; ++b) s += blockHist[(size_t)b * K + k];
    segsum[(size_t)seg * K + k] = s;
}

// exclusive scan over bucket totals -> base[0..K], gcur[k] = base[k]
__global__ __launch_bounds__(1024) void basescan_kernel(
    const int* __restrict__ segsum, int* __restrict__ base,
    int* __restrict__ gcur, int K)
{
    __shared__ int sm[1024];
    const int t = threadIdx.x;
    const int chunk = (K + 1023) / 1024;
    const int b0 = min(t * chunk, K);
    const int e0 = min(b0 + chunk, K);
    int s = 0;
    for (int i = b0; i < e0; ++i)
        s += segsum[i] + segsum[K + i] + segsum[2 * K + i] + segsum[3 * K + i];
    sm[t] = s;
    __syncthreads();
    for (int off = 1; off < 1024; off <<= 1) {
        int v = (t >= off) ? sm[t - off] : 0;
        __syncthreads();
        if (t >= off) sm[t] += v;
        __syncthreads();
    }
    int run = (t == 0) ? 0 : sm[t - 1];
    for (int i = b0; i < e0; ++i) {
        base[i] = run;
        gcur[i] = run;
        run += segsum[i] + segsum[K + i] + segsum[2 * K + i] + segsum[3 * K + i];
    }
    if (e0 == K && b0 < K) base[K] = run;
}

// two-pass scatter: local hist -> claim bucket ranges via global atomic ->
// write packed (src<<6)|dstLocal grouped by bucket.
__global__ __launch_bounds__(256) void scatterB_kernel(
    const int* __restrict__ src, const int* __restrict__ dst,
    int* __restrict__ gcur, int* __restrict__ csrPacked,
    int E, int K, int chunk)
{
    __shared__ int h[KMAX];
    __shared__ int cur[KMAX];
    const int b = blockIdx.x, t = threadIdx.x;
    for (int i = t; i < K; i += 256) h[i] = 0;
    __syncthreads();
    const int beg = b * chunk;
    const int end = min(beg + chunk, E);
    for (int i = beg + t; i < end; i += 256)
        atomicAdd(&h[dst[i] >> BSHIFT], 1);
    __syncthreads();
    for (int i = t; i < K; i += 256) {
        int c = h[i];
        cur[i] = c ? atomicAdd(&gcur[i], c) : 0;
    }
    __syncthreads();
    for (int i = beg + t; i < end; i += 256) {
        int d = dst[i];
        int k = d >> BSHIFT;
        int r = atomicAdd(&cur[k], 1);   // LDS atomic
        csrPacked[r] = (src[i] << BSHIFT) | (d & (BSIZE - 1));
    }
}

// ---------------------------------------------------------------------------
// Fused per-bucket aggregate (LDS fp32 accumulators, ds_add_f32) + MFMA GEMM
// + bias + ReLU. One block per 64-node bucket. LDS acc = 64 KB.
// Gather: per edge, lane loads 2 dwords -> cols {2l,2l+1} and {128+2l,129+2l};
// ds_add banks = (2l+c)%32 -> 4-way conflict (1.58x, hidden under gather).
// ---------------------------------------------------------------------------
__global__ __launch_bounds__(256) void bucket_agg_gemm_kernel(
    const unsigned short* __restrict__ fbf,
    const int* __restrict__ csrPacked,
    const int* __restrict__ base,
    const unsigned short* __restrict__ Wt,
    const float* __restrict__ bias,
    float* __restrict__ out, int N)
{
    __shared__ float acc[BSIZE][D];          // 64 KB

    const int k    = blockIdx.x;
    const int t    = threadIdx.x;
    const int wave = t >> 6;
    const int lane = t & 63;

    // zero accumulators
    float4 z = make_float4(0.f, 0.f, 0.f, 0.f);
    for (int i = t; i < BSIZE * D / 4; i += 256)
        reinterpret_cast<float4*>(acc)[i] = z;
    __syncthreads();

    const int beg = base[k], end = base[k + 1];
    const int c0 = 2 * lane, c1 = 2 * lane + 1;

    for (int j = beg + (wave << 2); j < end; j += 16) {
        if (j + 4 <= end) {
            int p0 = csrPacked[j + 0];
            int p1 = csrPacked[j + 1];
            int p2 = csrPacked[j + 2];
            int p3 = csrPacked[j + 3];
            const unsigned int* r0 = reinterpret_cast<const unsigned int*>(
                fbf + ((size_t)(p0 >> BSHIFT) << 8));
            const unsigned int* r1 = reinterpret_cast<const unsigned int*>(
                fbf + ((size_t)(p1 >> BSHIFT) << 8));
            const unsigned int* r2 = reinterpret_cast<const unsigned int*>(
                fbf + ((size_t)(p2 >> BSHIFT) << 8));
            const unsigned int* r3 = reinterpret_cast<const unsigned int*>(
                fbf + ((size_t)(p3 >> BSHIFT) << 8));
            unsigned int a0 = r0[lane], b0 = r0[64 + lane];
            unsigned int a1 = r1[lane], b1 = r1[64 + lane];
            unsigned int a2 = r2[lane], b2 = r2[64 + lane];
            unsigned int a3 = r3[lane], b3 = r3[64 + lane];
            int d0 = p0 & (BSIZE - 1), d1 = p1 & (BSIZE - 1);
            int d2 = p2 & (BSIZE - 1), d3 = p3 & (BSIZE - 1);
            atomicAdd(&acc[d0][c0],       bf_lo(a0));
            atomicAdd(&acc[d0][c1],       bf_hi(a0));
            atomicAdd(&acc[d0][128 + c0], bf_lo(b0));
            atomicAdd(&acc[d0][128 + c1], bf_hi(b0));
            atomicAdd(&acc[d1][c0],       bf_lo(a1));
            atomicAdd(&acc[d1][c1],       bf_hi(a1));
            atomicAdd(&acc[d1][128 + c0], bf_lo(b1));
            atomicAdd(&acc[d1][128 + c1], bf_hi(b1));
            atomicAdd(&acc[d2][c0],       bf_lo(a2));
            atomicAdd(&acc[d2][c1],       bf_hi(a2));
            atomicAdd(&acc[d2][128 + c0], bf_lo(b2));
            atomicAdd(&acc[d2][128 + c1], bf_hi(b2));
            atomicAdd(&acc[d3][c0],       bf_lo(a3));
            atomicAdd(&acc[d3][c1],       bf_hi(a3));
            atomicAdd(&acc[d3][128 + c0], bf_lo(b3));
            atomicAdd(&acc[d3][128 + c1], bf_hi(b3));
        } else {
            for (int e = 0; j + e < end; ++e) {
                int p = csrPacked[j + e];
                const unsigned int* r = reinterpret_cast<const unsigned int*>(
                    fbf + ((size_t)(p >> BSHIFT) << 8));
                unsigned int a = r[lane], bb = r[64 + lane];
                int dl = p & (BSIZE - 1);
                atomicAdd(&acc[dl][c0],       bf_lo(a));
                atomicAdd(&acc[dl][c1],       bf_hi(a));
                atomicAdd(&acc[dl][128 + c0], bf_lo(bb));
                atomicAdd(&acc[dl][128 + c1], bf_hi(bb));
            }
        }
    }
    __syncthreads();

    // ---- GEMM phase: wave w computes rows [16w, 16w+16) of this bucket ----
    const int lr = lane & 15;
    const int lg = lane >> 4;

    bf16x8 afr[8];
#pragma unroll
    for (int ks = 0; ks < 8; ++ks) {
        const float* ap = &acc[(wave << 4) + lr][ks * 32 + lg * 8];
        float4 v0 = *reinterpret_cast<const float4*>(ap);
        float4 v1 = *reinterpret_cast<const float4*>(ap + 4);
        bf16x8 f;
        f[0] = (short)f2bf(v0.x); f[1] = (short)f2bf(v0.y);
        f[2] = (short)f2bf(v0.z); f[3] = (short)f2bf(v0.w);
        f[4] = (short)f2bf(v1.x); f[5] = (short)f2bf(v1.y);
        f[6] = (short)f2bf(v1.z); f[7] = (short)f2bf(v1.w);
        afr[ks] = f;
    }

    const int nodeBase = (k << BSHIFT) + (wave << 4) + (lg << 2);
    for (int ct = 0; ct < 16; ++ct) {
        f32x4 o = {0.f, 0.f, 0.f, 0.f};
        const unsigned short* bp = Wt + (size_t)(ct * 16 + lr) * D + lg * 8;
#pragma unroll
        for (int ks = 0; ks < 8; ++ks) {
            bf16x8 bfr = *reinterpret_cast<const bf16x8*>(bp + ks * 32);
            o = __builtin_amdgcn_mfma_f32_16x16x32_bf16(afr[ks], bfr, o, 0, 0, 0);
        }
        const float bv = bias[ct * 16 + lr];
#pragma unroll
        for (int jj = 0; jj < 4; ++jj) {
            int node = nodeBase + jj;
            if (node < N) {
                float v = o[jj] + bv;
                out[(size_t)node * D + ct * 16 + lr] = v > 0.f ? v : 0.f;
            }
        }
    }
}

// ---------------------------------------------------------------------------
// Fallback kernels (ws too small): direct atomic scatter + VALU linear.
// ---------------------------------------------------------------------------
__global__ __launch_bounds__(256) void scatter_kernel(
    const float* __restrict__ feature, const int* __restrict__ src,
    const int* __restrict__ dst, float* __restrict__ agg, int E)
{
    int edge = blockIdx.x * (blockDim.x >> 6) + (threadIdx.x >> 6);
    int lane = threadIdx.x & 63;
    if (edge >= E) return;
    int s = src[edge];
    int d = dst[edge];
    const float4 v = *reinterpret_cast<const float4*>(feature + (size_t)s * D + lane * 4);
    float* o = agg + (size_t)d * D + lane * 4;
    atomicAdd(o + 0, v.x);
    atomicAdd(o + 1, v.y);
    atomicAdd(o + 2, v.z);
    atomicAdd(o + 3, v.w);
}

#define BM 32
__global__ __launch_bounds__(256) void linear_relu_kernel(
    float* __restrict__ h, const float* __restrict__ W,
    const float* __restrict__ b, int n_nodes)
{
    __shared__ float sA[BM][D];
    const int node0 = blockIdx.x * BM;
    const int t = threadIdx.x;
    for (int m = 0; m < BM; ++m) {
        int nd = node0 + m;
        sA[m][t] = (nd < n_nodes) ? h[(size_t)nd * D + t] : 0.0f;
    }
    __syncthreads();
    float acc[BM];
#pragma unroll
    for (int m = 0; m < BM; ++m) acc[m] = 0.0f;
    for (int kk = 0; kk < D; ++kk) {
        float w = W[kk * D + t];
#pragma unroll
        for (int m = 0; m < BM; ++m) acc[m] += sA[m][kk] * w;
    }
    const float bias = b[t];
    for (int m = 0; m < BM; ++m) {
        int nd = node0 + m;
        if (nd < n_nodes) {
            float v = acc[m] + bias;
            h[(size_t)nd * D + t] = v > 0.0f ? v : 0.0f;
        }
    }
}

// ---------------------------------------------------------------------------
extern "C" void kernel_launch(void* const* d_in, const int* in_sizes, int n_in,
                              void* d_out, int out_size, void* d_ws, size_t ws_size,
                              hipStream_t stream)
{
    const float* feature = (const float*)d_in[0];
    const int*   src     = (const int*)d_in[1];
    const int*   dst     = (const int*)d_in[2];
    const float* W       = (const float*)d_in[3];
    const float* b       = (const float*)d_in[4];
    float*       out     = (float*)d_out;

    const int E = in_sizes[1];
    const int N = in_sizes[0] / D;
    const int K = (N + BSIZE - 1) >> BSHIFT;        // buckets
    const int chunk = (E + NB_P - 1) / NB_P;

    // ---- workspace layout -------------------------------------------------
    size_t off = 0;
    auto alloc = [&](size_t bytes, size_t align) {
        off = (off + align - 1) / align * align;
        size_t r = off; off += bytes; return r;
    };
    size_t o_bh     = alloc((size_t)NB_P * K * 4, 16);
    size_t o_seg    = alloc((size_t)4 * K * 4, 16);
    size_t o_base   = alloc((size_t)(K + 1) * 4, 16);
    size_t o_gcur   = alloc((size_t)K * 4, 16);
    size_t o_packed = alloc((size_t)E * 4, 16);
    size_t o_wt     = alloc((size_t)D * D * 2, 16);
    size_t o_fbf    = alloc((size_t)N * D * 2, 16);
    size_t need_full = off;

    char* ws = (char*)d_ws;

    if (ws_size >= need_full && K <= KMAX) {
        int* blockHist = (int*)(ws + o_bh);
        int* segsum    = (int*)(ws + o_seg);
        int* base      = (int*)(ws + o_base);
        int* gcur      = (int*)(ws + o_gcur);
        int* csrPacked = (int*)(ws + o_packed);
        unsigned short* Wt  = (unsigned short*)(ws + o_wt);
        unsigned short* fbf = (unsigned short*)(ws + o_fbf);

        {   // feature -> bf16
            long n8 = (long)N * D / 8;
            conv_feature_kernel<<<(int)((n8 + 255) / 256), 256, 0, stream>>>(
                feature, fbf, n8);
        }
        conv_w_kernel<<<(D * D / 4 + 255) / 256, 256, 0, stream>>>(W, Wt);

        histA_kernel<<<NB_P, 256, 0, stream>>>(dst, blockHist, E, K, chunk);
        {
            dim3 g((K + 255) / 256, 4);
            colsumA_kernel<<<g, 256, 0, stream>>>(blockHist, segsum, K);
        }
        basescan_kernel<<<1, 1024, 0, stream>>>(segsum, base, gcur, K);
        scatterB_kernel<<<NB_P, 256, 0, stream>>>(
            src, dst, gcur, csrPacked, E, K, chunk);

        bucket_agg_gemm_kernel<<<K, 256, 0, stream>>>(
            fbf, csrPacked, base, Wt, b, out, N);
    } else {
        hipMemsetAsync(d_out, 0, (size_t)out_size * sizeof(float), stream);
        scatter_kernel<<<(E + 3) / 4, 256, 0, stream>>>(feature, src, dst, out, E);
        linear_relu_kernel<<<(N + BM - 1) / BM, 256, 0, stream>>>(out, W, b, N);
    }
}

// Round 6
// 547.644 us; speedup vs baseline: 8.7691x; 8.7691x over previous
//
#include <hip/hip_runtime.h>

#define D 256
#define BSHIFT 6
#define BSIZE 64          // nodes per bucket
#define KMAX 2048         // max buckets (LDS arrays)
#define NB_P 256          // partition blocks

using bf16x8 = __attribute__((ext_vector_type(8))) short;
using f32x4  = __attribute__((ext_vector_type(4))) float;

__device__ inline float bf_lo(unsigned int u) {
    return __builtin_bit_cast(float, u << 16);
}
__device__ inline float bf_hi(unsigned int u) {
    return __builtin_bit_cast(float, u & 0xffff0000u);
}
__device__ inline unsigned short f2bf(float f) {
    unsigned int x = __builtin_bit_cast(unsigned int, f);
    unsigned int r = (x + 0x7fffu + ((x >> 16) & 1u)) >> 16;   // RNE
    return (unsigned short)r;
}

// ---------------------------------------------------------------------------
// Converters
// ---------------------------------------------------------------------------
__global__ __launch_bounds__(256) void conv_feature_kernel(
    const float* __restrict__ f, unsigned short* __restrict__ o, long n8)
{
    long i = (long)blockIdx.x * blockDim.x + threadIdx.x;   // 8 floats each
    if (i >= n8) return;
    const float4* p = reinterpret_cast<const float4*>(f + i * 8);
    float4 v0 = p[0], v1 = p[1];
    uint4 r;
    r.x = (unsigned int)f2bf(v0.x) | ((unsigned int)f2bf(v0.y) << 16);
    r.y = (unsigned int)f2bf(v0.z) | ((unsigned int)f2bf(v0.w) << 16);
    r.z = (unsigned int)f2bf(v1.x) | ((unsigned int)f2bf(v1.y) << 16);
    r.w = (unsigned int)f2bf(v1.z) | ((unsigned int)f2bf(v1.w) << 16);
    *reinterpret_cast<uint4*>(o + i * 8) = r;
}

// Wt[n][k] = bf16(W[k][n])
__global__ __launch_bounds__(256) void conv_w_kernel(
    const float* __restrict__ W, unsigned short* __restrict__ Wt)
{
    int i = blockIdx.x * blockDim.x + threadIdx.x;   // 4 k's each
    if (i >= D * D / 4) return;
    int n  = i >> 6;
    int k0 = (i & 63) * 4;
    float a = W[(size_t)(k0 + 0) * D + n];
    float b = W[(size_t)(k0 + 1) * D + n];
    float c = W[(size_t)(k0 + 2) * D + n];
    float d = W[(size_t)(k0 + 3) * D + n];
    uint2 r;
    r.x = (unsigned int)f2bf(a) | ((unsigned int)f2bf(b) << 16);
    r.y = (unsigned int)f2bf(c) | ((unsigned int)f2bf(d) << 16);
    *reinterpret_cast<uint2*>(Wt + (size_t)n * D + k0) = r;
}

// ---------------------------------------------------------------------------
// Bucket partition (round-5 path, cheap): per-block LDS histograms ->
// 4x64 segment sums -> base scan -> scatter with global atomic range claims.
// ---------------------------------------------------------------------------
__global__ __launch_bounds__(256) void histA_kernel(
    const int* __restrict__ dst, int* __restrict__ blockHist,
    int E, int K, int chunk)
{
    __shared__ int h[KMAX];
    const int b = blockIdx.x, t = threadIdx.x;
    for (int i = t; i < K; i += 256) h[i] = 0;
    __syncthreads();
    const int beg = b * chunk;
    const int end = min(beg + chunk, E);
    for (int i = beg + t; i < end; i += 256)
        atomicAdd(&h[dst[i] >> BSHIFT], 1);
    __syncthreads();
    for (int i = t; i < K; i += 256)
        blockHist[(size_t)b * K + i] = h[i];
}

__global__ __launch_bounds__(256) void colsumA_kernel(
    const int* __restrict__ blockHist, int* __restrict__ segsum, int K)
{
    int k = blockIdx.x * 256 + threadIdx.x;
    int seg = blockIdx.y;
    if (k >= K) return;
    int s = 0;
    const int b0 = seg * 64;
    for (int b = b0; b < b0 + 64; ++b) s += blockHist[(size_t)b * K + k];
    segsum[(size_t)seg * K + k] = s;
}

__global__ __launch_bounds__(1024) void basescan_kernel(
    const int* __restrict__ segsum, int* __restrict__ base,
    int* __restrict__ gcur, int K)
{
    __shared__ int sm[1024];
    const int t = threadIdx.x;
    const int chunk = (K + 1023) / 1024;
    const int b0 = min(t * chunk, K);
    const int e0 = min(b0 + chunk, K);
    int s = 0;
    for (int i = b0; i < e0; ++i)
        s += segsum[i] + segsum[K + i] + segsum[2 * K + i] + segsum[3 * K + i];
    sm[t] = s;
    __syncthreads();
    for (int off = 1; off < 1024; off <<= 1) {
        int v = (t >= off) ? sm[t - off] : 0;
        __syncthreads();
        if (t >= off) sm[t] += v;
        __syncthreads();
    }
    int run = (t == 0) ? 0 : sm[t - 1];
    for (int i = b0; i < e0; ++i) {
        base[i] = run;
        gcur[i] = run;
        run += segsum[i] + segsum[K + i] + segsum[2 * K + i] + segsum[3 * K + i];
    }
    if (e0 == K && b0 < K) base[K] = run;
}

__global__ __launch_bounds__(256) void scatterB_kernel(
    const int* __restrict__ src, const int* __restrict__ dst,
    int* __restrict__ gcur, int* __restrict__ csrPacked,
    int E, int K, int chunk)
{
    __shared__ int h[KMAX];
    __shared__ int cur[KMAX];
    const int b = blockIdx.x, t = threadIdx.x;
    for (int i = t; i < K; i += 256) h[i] = 0;
    __syncthreads();
    const int beg = b * chunk;
    const int end = min(beg + chunk, E);
    for (int i = beg + t; i < end; i += 256)
        atomicAdd(&h[dst[i] >> BSHIFT], 1);
    __syncthreads();
    for (int i = t; i < K; i += 256) {
        int c = h[i];
        cur[i] = c ? atomicAdd(&gcur[i], c) : 0;
    }
    __syncthreads();
    for (int i = beg + t; i < end; i += 256) {
        int d = dst[i];
        int k = d >> BSHIFT;
        int r = atomicAdd(&cur[k], 1);   // LDS atomic
        csrPacked[r] = (src[i] << BSHIFT) | (d & (BSIZE - 1));
    }
}

// Per-bucket counting sort over 64 local nodes -> csr_src, offsets, counts.
__global__ __launch_bounds__(256) void sortC_kernel(
    const int* __restrict__ csrPacked, const int* __restrict__ base,
    int* __restrict__ csr_src, int* __restrict__ offsets,
    int* __restrict__ counts, int N)
{
    __shared__ int hist[BSIZE];
    __shared__ int pref[BSIZE];
    __shared__ int cur[BSIZE];
    const int k = blockIdx.x, t = threadIdx.x;
    const int beg = base[k], end = base[k + 1];

    if (t < BSIZE) hist[t] = 0;
    __syncthreads();
    for (int i = beg + t; i < end; i += 256)
        atomicAdd(&hist[csrPacked[i] & (BSIZE - 1)], 1);
    __syncthreads();
    if (t == 0) {
        int run = 0;
        for (int j = 0; j < BSIZE; ++j) { pref[j] = run; run += hist[j]; }
    }
    __syncthreads();
    if (t < BSIZE) {
        cur[t] = pref[t];
        int node = (k << BSHIFT) + t;
        if (node < N) {
            offsets[node] = beg + pref[t];
            counts[node]  = hist[t];
        }
    }
    __syncthreads();
    for (int i = beg + t; i < end; i += 256) {
        int p = csrPacked[i];
        int r = atomicAdd(&cur[p & (BSIZE - 1)], 1);   // LDS atomic
        csr_src[beg + r] = p >> BSHIFT;
    }
}

// ---------------------------------------------------------------------------
// Aggregate v2: one wave per node, half-wave edge split.
// Lanes 0-31 take even edges, 32-63 odd edges; each lane loads uint4
// (16 B = 8 bf16 cols: cols 8*sub .. 8*sub+7), fp32 accumulate in 8 regs,
// final __shfl_xor(...,32) merge, bf16 row write by lanes 0-31.
// ---------------------------------------------------------------------------
__global__ __launch_bounds__(256) void aggregate_kernel(
    const unsigned short* __restrict__ fbf,
    const int* __restrict__ csr_src,
    const int* __restrict__ offsets,
    const int* __restrict__ counts,
    unsigned short* __restrict__ aggb, int N)
{
    int node = blockIdx.x * 4 + (threadIdx.x >> 6);
    int lane = threadIdx.x & 63;
    if (node >= N) return;

    const int sub  = lane & 31;
    const int half = lane >> 5;
    const int beg = offsets[node];
    const int cnt = counts[node];

    float a0 = 0.f, a1 = 0.f, a2 = 0.f, a3 = 0.f;
    float a4 = 0.f, a5 = 0.f, a6 = 0.f, a7 = 0.f;

    const size_t colOff = (size_t)(sub << 3);

    int j = 0;
    for (; j + 3 < cnt; j += 4) {
        int s0 = csr_src[beg + j + half];
        int s1 = csr_src[beg + j + 2 + half];
        uint4 v0 = *reinterpret_cast<const uint4*>(fbf + ((size_t)s0 << 8) + colOff);
        uint4 v1 = *reinterpret_cast<const uint4*>(fbf + ((size_t)s1 << 8) + colOff);
        a0 += bf_lo(v0.x); a1 += bf_hi(v0.x); a2 += bf_lo(v0.y); a3 += bf_hi(v0.y);
        a4 += bf_lo(v0.z); a5 += bf_hi(v0.z); a6 += bf_lo(v0.w); a7 += bf_hi(v0.w);
        a0 += bf_lo(v1.x); a1 += bf_hi(v1.x); a2 += bf_lo(v1.y); a3 += bf_hi(v1.y);
        a4 += bf_lo(v1.z); a5 += bf_hi(v1.z); a6 += bf_lo(v1.w); a7 += bf_hi(v1.w);
    }
    if (j + 1 < cnt) {
        int s0 = csr_src[beg + j + half];
        uint4 v0 = *reinterpret_cast<const uint4*>(fbf + ((size_t)s0 << 8) + colOff);
        a0 += bf_lo(v0.x); a1 += bf_hi(v0.x); a2 += bf_lo(v0.y); a3 += bf_hi(v0.y);
        a4 += bf_lo(v0.z); a5 += bf_hi(v0.z); a6 += bf_lo(v0.w); a7 += bf_hi(v0.w);
        j += 2;
    }
    if (j < cnt && half == 0) {
        int s0 = csr_src[beg + j];
        uint4 v0 = *reinterpret_cast<const uint4*>(fbf + ((size_t)s0 << 8) + colOff);
        a0 += bf_lo(v0.x); a1 += bf_hi(v0.x); a2 += bf_lo(v0.y); a3 += bf_hi(v0.y);
        a4 += bf_lo(v0.z); a5 += bf_hi(v0.z); a6 += bf_lo(v0.w); a7 += bf_hi(v0.w);
    }

    // merge halves (lane l += lane l^32)
    a0 += __shfl_xor(a0, 32); a1 += __shfl_xor(a1, 32);
    a2 += __shfl_xor(a2, 32); a3 += __shfl_xor(a3, 32);
    a4 += __shfl_xor(a4, 32); a5 += __shfl_xor(a5, 32);
    a6 += __shfl_xor(a6, 32); a7 += __shfl_xor(a7, 32);

    if (half == 0) {
        uint4 r;
        r.x = (unsigned int)f2bf(a0) | ((unsigned int)f2bf(a1) << 16);
        r.y = (unsigned int)f2bf(a2) | ((unsigned int)f2bf(a3) << 16);
        r.z = (unsigned int)f2bf(a4) | ((unsigned int)f2bf(a5) << 16);
        r.w = (unsigned int)f2bf(a6) | ((unsigned int)f2bf(a7) << 16);
        *reinterpret_cast<uint4*>(aggb + ((size_t)node << 8) + colOff) = r;
    }
}

// ---------------------------------------------------------------------------
// MFMA GEMM: out[M][256] = relu(aggb[M][256] @ W + b), W as Wt[n][k] bf16.
// One wave per 16 rows; A fragments from bf16 aggb (single dwordx4 loads).
// ---------------------------------------------------------------------------
__global__ __launch_bounds__(256) void gemm_kernel(
    const unsigned short* __restrict__ A,    // [M][256] bf16
    const unsigned short* __restrict__ Wt,   // [256][256] bf16, Wt[n][k]
    const float* __restrict__ bias,
    float* __restrict__ out, int M)
{
    const int wave = threadIdx.x >> 6;
    const int lane = threadIdx.x & 63;
    const int row0 = (blockIdx.x * 4 + wave) * 16;
    if (row0 >= M) return;

    const int lr = lane & 15;
    const int lg = lane >> 4;

    bf16x8 a[8];
    const unsigned short* ap = A + (size_t)(row0 + lr) * D + lg * 8;
#pragma unroll
    for (int ks = 0; ks < 8; ++ks)
        a[ks] = *reinterpret_cast<const bf16x8*>(ap + ks * 32);

    for (int ct = 0; ct < 16; ++ct) {
        f32x4 acc = {0.f, 0.f, 0.f, 0.f};
        const unsigned short* bp = Wt + (size_t)(ct * 16 + lr) * D + lg * 8;
#pragma unroll
        for (int ks = 0; ks < 8; ++ks) {
            bf16x8 bfr = *reinterpret_cast<const bf16x8*>(bp + ks * 32);
            acc = __builtin_amdgcn_mfma_f32_16x16x32_bf16(a[ks], bfr, acc, 0, 0, 0);
        }
        const float bv = bias[ct * 16 + lr];
#pragma unroll
        for (int jj = 0; jj < 4; ++jj) {
            float v = acc[jj] + bv;
            out[(size_t)(row0 + lg * 4 + jj) * D + ct * 16 + lr] = v > 0.f ? v : 0.f;
        }
    }
}

// ---------------------------------------------------------------------------
// Fallback kernels (ws too small): direct atomic scatter + VALU linear.
// ---------------------------------------------------------------------------
__global__ __launch_bounds__(256) void scatter_kernel(
    const float* __restrict__ feature, const int* __restrict__ src,
    const int* __restrict__ dst, float* __restrict__ agg, int E)
{
    int edge = blockIdx.x * (blockDim.x >> 6) + (threadIdx.x >> 6);
    int lane = threadIdx.x & 63;
    if (edge >= E) return;
    int s = src[edge];
    int d = dst[edge];
    const float4 v = *reinterpret_cast<const float4*>(feature + (size_t)s * D + lane * 4);
    float* o = agg + (size_t)d * D + lane * 4;
    atomicAdd(o + 0, v.x);
    atomicAdd(o + 1, v.y);
    atomicAdd(o + 2, v.z);
    atomicAdd(o + 3, v.w);
}

#define BM 32
__global__ __launch_bounds__(256) void linear_relu_kernel(
    float* __restrict__ h, const float* __restrict__ W,
    const float* __restrict__ b, int n_nodes)
{
    __shared__ float sA[BM][D];
    const int node0 = blockIdx.x * BM;
    const int t = threadIdx.x;
    for (int m = 0; m < BM; ++m) {
        int nd = node0 + m;
        sA[m][t] = (nd < n_nodes) ? h[(size_t)nd * D + t] : 0.0f;
    }
    __syncthreads();
    float acc[BM];
#pragma unroll
    for (int m = 0; m < BM; ++m) acc[m] = 0.0f;
    for (int kk = 0; kk < D; ++kk) {
        float w = W[kk * D + t];
#pragma unroll
        for (int m = 0; m < BM; ++m) acc[m] += sA[m][kk] * w;
    }
    const float bias = b[t];
    for (int m = 0; m < BM; ++m) {
        int nd = node0 + m;
        if (nd < n_nodes) {
            float v = acc[m] + bias;
            h[(size_t)nd * D + t] = v > 0.0f ? v : 0.0f;
        }
    }
}

// ---------------------------------------------------------------------------
extern "C" void kernel_launch(void* const* d_in, const int* in_sizes, int n_in,
                              void* d_out, int out_size, void* d_ws, size_t ws_size,
                              hipStream_t stream)
{
    const float* feature = (const float*)d_in[0];
    const int*   src     = (const int*)d_in[1];
    const int*   dst     = (const int*)d_in[2];
    const float* W       = (const float*)d_in[3];
    const float* b       = (const float*)d_in[4];
    float*       out     = (float*)d_out;

    const int E = in_sizes[1];
    const int N = in_sizes[0] / D;
    const int K = (N + BSIZE - 1) >> BSHIFT;        // buckets
    const int chunk = (E + NB_P - 1) / NB_P;

    // ---- workspace layout -------------------------------------------------
    size_t off = 0;
    auto alloc = [&](size_t bytes, size_t align) {
        off = (off + align - 1) / align * align;
        size_t r = off; off += bytes; return r;
    };
    size_t o_bh     = alloc((size_t)NB_P * K * 4, 16);
    size_t o_seg    = alloc((size_t)4 * K * 4, 16);
    size_t o_base   = alloc((size_t)(K + 1) * 4, 16);
    size_t o_gcur   = alloc((size_t)K * 4, 16);
    size_t o_packed = alloc((size_t)E * 4, 16);
    size_t o_csr    = alloc((size_t)E * 4, 16);
    size_t o_off    = alloc((size_t)N * 4, 16);
    size_t o_cnt    = alloc((size_t)N * 4, 16);
    size_t o_wt     = alloc((size_t)D * D * 2, 16);
    size_t o_fbf    = alloc((size_t)N * D * 2, 16);
    size_t o_aggb   = alloc((size_t)N * D * 2, 16);
    size_t need_full = off;

    char* ws = (char*)d_ws;

    if (ws_size >= need_full && K <= KMAX) {
        int* blockHist = (int*)(ws + o_bh);
        int* segsum    = (int*)(ws + o_seg);
        int* base      = (int*)(ws + o_base);
        int* gcur      = (int*)(ws + o_gcur);
        int* csrPacked = (int*)(ws + o_packed);
        int* csr_src   = (int*)(ws + o_csr);
        int* offsets   = (int*)(ws + o_off);
        int* counts    = (int*)(ws + o_cnt);
        unsigned short* Wt   = (unsigned short*)(ws + o_wt);
        unsigned short* fbf  = (unsigned short*)(ws + o_fbf);
        unsigned short* aggb = (unsigned short*)(ws + o_aggb);

        {   // feature -> bf16
            long n8 = (long)N * D / 8;
            conv_feature_kernel<<<(int)((n8 + 255) / 256), 256, 0, stream>>>(
                feature, fbf, n8);
        }
        conv_w_kernel<<<(D * D / 4 + 255) / 256, 256, 0, stream>>>(W, Wt);

        histA_kernel<<<NB_P, 256, 0, stream>>>(dst, blockHist, E, K, chunk);
        {
            dim3 g((K + 255) / 256, 4);
            colsumA_kernel<<<g, 256, 0, stream>>>(blockHist, segsum, K);
        }
        basescan_kernel<<<1, 1024, 0, stream>>>(segsum, base, gcur, K);
        scatterB_kernel<<<NB_P, 256, 0, stream>>>(
            src, dst, gcur, csrPacked, E, K, chunk);
        sortC_kernel<<<K, 256, 0, stream>>>(
            csrPacked, base, csr_src, offsets, counts, N);

        aggregate_kernel<<<(N + 3) / 4, 256, 0, stream>>>(
            fbf, csr_src, offsets, counts, aggb, N);

        gemm_kernel<<<(N + 63) / 64, 256, 0, stream>>>(aggb, Wt, b, out, N);
    } else {
        hipMemsetAsync(d_out, 0, (size_t)out_size * sizeof(float), stream);
        scatter_kernel<<<(E + 3) / 4, 256, 0, stream>>>(feature, src, dst, out, E);
        linear_relu_kernel<<<(N + BM - 1) / BM, 256, 0, stream>>>(out, W, b, N);
    }
}

// Round 7
// 542.276 us; speedup vs baseline: 8.8559x; 1.0099x over previous
//
#include <hip/hip_runtime.h>

#define D 256
#define BSHIFT 6
#define BSIZE 64          // nodes per bucket
#define KMAX 2048         // max buckets (LDS hist)
#define NB_P 256          // partition blocks
#define CAP 3072          // max edges per bucket handled by LDS sort (E[X]=2048, sigma=45)

using bf16x8 = __attribute__((ext_vector_type(8))) short;
using f32x4  = __attribute__((ext_vector_type(4))) float;

__device__ inline float bf_lo(unsigned int u) {
    return __builtin_bit_cast(float, u << 16);
}
__device__ inline float bf_hi(unsigned int u) {
    return __builtin_bit_cast(float, u & 0xffff0000u);
}
__device__ inline unsigned short f2bf(float f) {
    unsigned int x = __builtin_bit_cast(unsigned int, f);
    unsigned int r = (x + 0x7fffu + ((x >> 16) & 1u)) >> 16;   // RNE
    return (unsigned short)r;
}

// ---------------------------------------------------------------------------
// prep: conv_feature || conv_w || histA fused via blockIdx range split.
// ---------------------------------------------------------------------------
__global__ __launch_bounds__(256) void prep_kernel(
    const float* __restrict__ feature, unsigned short* __restrict__ fbf, long n8,
    const float* __restrict__ W, unsigned short* __restrict__ Wt,
    const int* __restrict__ dst, int* __restrict__ blockHist,
    int E, int K, int chunk, int nConvF, int nConvW)
{
    __shared__ int h[KMAX];
    const int b = blockIdx.x, t = threadIdx.x;

    if (b < nConvF) {
        long i = (long)b * 256 + t;
        if (i < n8) {
            const float4* p = reinterpret_cast<const float4*>(feature + i * 8);
            float4 v0 = p[0], v1 = p[1];
            uint4 r;
            r.x = (unsigned int)f2bf(v0.x) | ((unsigned int)f2bf(v0.y) << 16);
            r.y = (unsigned int)f2bf(v0.z) | ((unsigned int)f2bf(v0.w) << 16);
            r.z = (unsigned int)f2bf(v1.x) | ((unsigned int)f2bf(v1.y) << 16);
            r.w = (unsigned int)f2bf(v1.z) | ((unsigned int)f2bf(v1.w) << 16);
            *reinterpret_cast<uint4*>(fbf + i * 8) = r;
        }
        return;
    }
    if (b < nConvF + nConvW) {
        int i = (b - nConvF) * 256 + t;
        if (i < D * D / 4) {
            int n  = i >> 6;
            int k0 = (i & 63) * 4;
            float a  = W[(size_t)(k0 + 0) * D + n];
            float bb = W[(size_t)(k0 + 1) * D + n];
            float c  = W[(size_t)(k0 + 2) * D + n];
            float d  = W[(size_t)(k0 + 3) * D + n];
            uint2 r;
            r.x = (unsigned int)f2bf(a) | ((unsigned int)f2bf(bb) << 16);
            r.y = (unsigned int)f2bf(c) | ((unsigned int)f2bf(d) << 16);
            *reinterpret_cast<uint2*>(Wt + (size_t)n * D + k0) = r;
        }
        return;
    }
    // histA
    const int hb = b - nConvF - nConvW;
    for (int i = t; i < K; i += 256) h[i] = 0;
    __syncthreads();
    const int beg = hb * chunk;
    const int end = min(beg + chunk, E);
    for (int i = beg + t; i < end; i += 256)
        atomicAdd(&h[dst[i] >> BSHIFT], 1);
    __syncthreads();
    for (int i = t; i < K; i += 256)
        blockHist[(size_t)hb * K + i] = h[i];
}

// ---------------------------------------------------------------------------
// segment sums: segsum[seg][k] = sum over 64 blocks of blockHist[b][k]
// ---------------------------------------------------------------------------
__global__ __launch_bounds__(256) void colsumA_kernel(
    const int* __restrict__ blockHist, int* __restrict__ segsum, int K)
{
    int k = blockIdx.x * 256 + threadIdx.x;
    int seg = blockIdx.y;
    if (k >= K) return;
    int s = 0;
    const int b0 = seg * 64;
    for (int b = b0; b < b0 + 64; ++b) s += blockHist[(size_t)b * K + k];
    segsum[(size_t)seg * K + k] = s;
}

// exclusive scan over bucket totals -> base[0..K], gcur = base
__global__ __launch_bounds__(1024) void basescan_kernel(
    const int* __restrict__ segsum, int* __restrict__ base,
    int* __restrict__ gcur, int K)
{
    __shared__ int sm[1024];
    const int t = threadIdx.x;
    const int chunk = (K + 1023) / 1024;
    const int b0 = min(t * chunk, K);
    const int e0 = min(b0 + chunk, K);
    int s = 0;
    for (int i = b0; i < e0; ++i)
        s += segsum[i] + segsum[K + i] + segsum[2 * K + i] + segsum[3 * K + i];
    sm[t] = s;
    __syncthreads();
    for (int off = 1; off < 1024; off <<= 1) {
        int v = (t >= off) ? sm[t - off] : 0;
        __syncthreads();
        if (t >= off) sm[t] += v;
        __syncthreads();
    }
    int run = (t == 0) ? 0 : sm[t - 1];
    for (int i = b0; i < e0; ++i) {
        base[i] = run;
        gcur[i] = run;
        run += segsum[i] + segsum[K + i] + segsum[2 * K + i] + segsum[3 * K + i];
    }
    if (e0 == K && b0 < K) base[K] = run;
}

// ---------------------------------------------------------------------------
// scatterB v2: read own blockHist row (no dst re-histogram), claim bucket
// ranges via global atomic, scatter packed (src<<6)|dstLocal.
// ---------------------------------------------------------------------------
__global__ __launch_bounds__(256) void scatterB_kernel(
    const int* __restrict__ src, const int* __restrict__ dst,
    const int* __restrict__ blockHist, int* __restrict__ gcur,
    int* __restrict__ csrPacked, int E, int K, int chunk)
{
    __shared__ int cur[KMAX];
    const int b = blockIdx.x, t = threadIdx.x;
    for (int i = t; i < K; i += 256) {
        int c = blockHist[(size_t)b * K + i];
        cur[i] = c ? atomicAdd(&gcur[i], c) : 0;
    }
    __syncthreads();
    const int beg = b * chunk;
    const int end = min(beg + chunk, E);
    for (int i = beg + t; i < end; i += 256) {
        int d = dst[i];
        int k = d >> BSHIFT;
        int r = atomicAdd(&cur[k], 1);   // LDS atomic
        csrPacked[r] = (src[i] << BSHIFT) | (d & (BSIZE - 1));
    }
}

// ---------------------------------------------------------------------------
// Mega bucket kernel: one 256-thread block per 64-node bucket.
// P0: in-LDS counting sort of the bucket's packed edge list.
// P1: per-node register-accumulated gather (split-half uint4, shfl merge),
//     bf16 row written to padded LDS A.
// P2: in-block MFMA GEMM (64x256 @ 256x256) + bias + ReLU -> out.
// ---------------------------------------------------------------------------
__global__ __launch_bounds__(256) void bucket_kernel(
    const unsigned short* __restrict__ fbf,
    const int* __restrict__ csrPacked,
    const int* __restrict__ base,
    const unsigned short* __restrict__ Wt,
    const float* __restrict__ bias,
    float* __restrict__ out, int N)
{
    __shared__ int lsrc[CAP];
    __shared__ int nBeg[BSIZE], nCnt[BSIZE], nCur[BSIZE];
    __shared__ unsigned short A[BSIZE][D + 8];     // 528 B rows (pad vs bank conflicts)

    const int k    = blockIdx.x;
    const int t    = threadIdx.x;
    const int wave = t >> 6;
    const int lane = t & 63;
    const int beg  = base[k], end = base[k + 1];
    const int total = end - beg;

    const int sub  = lane & 31;
    const int half = lane >> 5;

    if (total <= CAP) {
        // ---- P0: counting sort into lsrc, grouped by local node ----
        if (t < BSIZE) nCnt[t] = 0;
        __syncthreads();
        for (int i = t; i < total; i += 256)
            atomicAdd(&nCnt[csrPacked[beg + i] & (BSIZE - 1)], 1);
        __syncthreads();
        if (t == 0) {
            int run = 0;
            for (int j = 0; j < BSIZE; ++j) { nBeg[j] = run; run += nCnt[j]; }
        }
        __syncthreads();
        if (t < BSIZE) nCur[t] = nBeg[t];
        __syncthreads();
        for (int i = t; i < total; i += 256) {
            int p = csrPacked[beg + i];
            int r = atomicAdd(&nCur[p & (BSIZE - 1)], 1);
            lsrc[r] = p >> BSHIFT;
        }
        __syncthreads();

        // ---- P1: gather-accumulate, 16 nodes per wave ----
        const size_t colOff = (size_t)(sub << 3);
        for (int ni = 0; ni < 16; ++ni) {
            const int l = (wave << 4) + ni;
            const int g = (k << BSHIFT) + l;
            float a0 = 0.f, a1 = 0.f, a2 = 0.f, a3 = 0.f;
            float a4 = 0.f, a5 = 0.f, a6 = 0.f, a7 = 0.f;
            if (g < N) {
                const int b0 = nBeg[l];
                const int cnt = nCnt[l];
                int j = 0;
                for (; j + 3 < cnt; j += 4) {
                    int s0 = lsrc[b0 + j + half];
                    int s1 = lsrc[b0 + j + 2 + half];
                    uint4 v0 = *reinterpret_cast<const uint4*>(fbf + ((size_t)s0 << 8) + colOff);
                    uint4 v1 = *reinterpret_cast<const uint4*>(fbf + ((size_t)s1 << 8) + colOff);
                    a0 += bf_lo(v0.x); a1 += bf_hi(v0.x); a2 += bf_lo(v0.y); a3 += bf_hi(v0.y);
                    a4 += bf_lo(v0.z); a5 += bf_hi(v0.z); a6 += bf_lo(v0.w); a7 += bf_hi(v0.w);
                    a0 += bf_lo(v1.x); a1 += bf_hi(v1.x); a2 += bf_lo(v1.y); a3 += bf_hi(v1.y);
                    a4 += bf_lo(v1.z); a5 += bf_hi(v1.z); a6 += bf_lo(v1.w); a7 += bf_hi(v1.w);
                }
                if (j + 1 < cnt) {
                    int s0 = lsrc[b0 + j + half];
                    uint4 v0 = *reinterpret_cast<const uint4*>(fbf + ((size_t)s0 << 8) + colOff);
                    a0 += bf_lo(v0.x); a1 += bf_hi(v0.x); a2 += bf_lo(v0.y); a3 += bf_hi(v0.y);
                    a4 += bf_lo(v0.z); a5 += bf_hi(v0.z); a6 += bf_lo(v0.w); a7 += bf_hi(v0.w);
                    j += 2;
                }
                if (j < cnt && half == 0) {
                    int s0 = lsrc[b0 + j];
                    uint4 v0 = *reinterpret_cast<const uint4*>(fbf + ((size_t)s0 << 8) + colOff);
                    a0 += bf_lo(v0.x); a1 += bf_hi(v0.x); a2 += bf_lo(v0.y); a3 += bf_hi(v0.y);
                    a4 += bf_lo(v0.z); a5 += bf_hi(v0.z); a6 += bf_lo(v0.w); a7 += bf_hi(v0.w);
                }
            }
            a0 += __shfl_xor(a0, 32); a1 += __shfl_xor(a1, 32);
            a2 += __shfl_xor(a2, 32); a3 += __shfl_xor(a3, 32);
            a4 += __shfl_xor(a4, 32); a5 += __shfl_xor(a5, 32);
            a6 += __shfl_xor(a6, 32); a7 += __shfl_xor(a7, 32);
            if (half == 0) {
                uint4 r;
                r.x = (unsigned int)f2bf(a0) | ((unsigned int)f2bf(a1) << 16);
                r.y = (unsigned int)f2bf(a2) | ((unsigned int)f2bf(a3) << 16);
                r.z = (unsigned int)f2bf(a4) | ((unsigned int)f2bf(a5) << 16);
                r.w = (unsigned int)f2bf(a6) | ((unsigned int)f2bf(a7) << 16);
                *reinterpret_cast<uint4*>(&A[l][sub << 3]) = r;
            }
        }
    } else {
        // ---- slow path (never expected): per-node scan of global list ----
        for (int ni = 0; ni < 16; ++ni) {
            const int l = (wave << 4) + ni;
            const int g = (k << BSHIFT) + l;
            float c0 = 0.f, c1 = 0.f, c2 = 0.f, c3 = 0.f;
            if (g < N) {
                for (int j = 0; j < total; ++j) {
                    int p = csrPacked[beg + j];
                    if ((p & (BSIZE - 1)) == l) {
                        uint2 v = *reinterpret_cast<const uint2*>(
                            fbf + ((size_t)(p >> BSHIFT) << 8) + (lane << 2));
                        c0 += bf_lo(v.x); c1 += bf_hi(v.x);
                        c2 += bf_lo(v.y); c3 += bf_hi(v.y);
                    }
                }
            }
            uint2 r;
            r.x = (unsigned int)f2bf(c0) | ((unsigned int)f2bf(c1) << 16);
            r.y = (unsigned int)f2bf(c2) | ((unsigned int)f2bf(c3) << 16);
            *reinterpret_cast<uint2*>(&A[l][lane << 2]) = r;
        }
    }
    __syncthreads();

    // ---- P2: GEMM 64x256 = A(64x256) @ W, + bias, ReLU ----
    const int lr = lane & 15;
    const int lg = lane >> 4;
    const int row = (wave << 4) + lr;

    bf16x8 afr[8];
#pragma unroll
    for (int ks = 0; ks < 8; ++ks)
        afr[ks] = *reinterpret_cast<const bf16x8*>(&A[row][ks * 32 + lg * 8]);

    const int nodeBase = (k << BSHIFT) + (wave << 4) + (lg << 2);
    for (int ct = 0; ct < 16; ++ct) {
        f32x4 acc = {0.f, 0.f, 0.f, 0.f};
        const unsigned short* bp = Wt + (size_t)(ct * 16 + lr) * D + lg * 8;
#pragma unroll
        for (int ks = 0; ks < 8; ++ks) {
            bf16x8 bfr = *reinterpret_cast<const bf16x8*>(bp + ks * 32);
            acc = __builtin_amdgcn_mfma_f32_16x16x32_bf16(afr[ks], bfr, acc, 0, 0, 0);
        }
        const float bv = bias[ct * 16 + lr];
#pragma unroll
        for (int jj = 0; jj < 4; ++jj) {
            int node = nodeBase + jj;
            if (node < N) {
                float v = acc[jj] + bv;
                out[(size_t)node * D + ct * 16 + lr] = v > 0.f ? v : 0.f;
            }
        }
    }
}

// ---------------------------------------------------------------------------
// Fallback kernels (ws too small): direct atomic scatter + VALU linear.
// ---------------------------------------------------------------------------
__global__ __launch_bounds__(256) void scatter_kernel(
    const float* __restrict__ feature, const int* __restrict__ src,
    const int* __restrict__ dst, float* __restrict__ agg, int E)
{
    int edge = blockIdx.x * (blockDim.x >> 6) + (threadIdx.x >> 6);
    int lane = threadIdx.x & 63;
    if (edge >= E) return;
    int s = src[edge];
    int d = dst[edge];
    const float4 v = *reinterpret_cast<const float4*>(feature + (size_t)s * D + lane * 4);
    float* o = agg + (size_t)d * D + lane * 4;
    atomicAdd(o + 0, v.x);
    atomicAdd(o + 1, v.y);
    atomicAdd(o + 2, v.z);
    atomicAdd(o + 3, v.w);
}

#define BM 32
__global__ __launch_bounds__(256) void linear_relu_kernel(
    float* __restrict__ h, const float* __restrict__ W,
    const float* __restrict__ b, int n_nodes)
{
    __shared__ float sA[BM][D];
    const int node0 = blockIdx.x * BM;
    const int t = threadIdx.x;
    for (int m = 0; m < BM; ++m) {
        int nd = node0 + m;
        sA[m][t] = (nd < n_nodes) ? h[(size_t)nd * D + t] : 0.0f;
    }
    __syncthreads();
    float acc[BM];
#pragma unroll
    for (int m = 0; m < BM; ++m) acc[m] = 0.0f;
    for (int kk = 0; kk < D; ++kk) {
        float w = W[kk * D + t];
#pragma unroll
        for (int m = 0; m < BM; ++m) acc[m] += sA[m][kk] * w;
    }
    const float bias = b[t];
    for (int m = 0; m < BM; ++m) {
        int nd = node0 + m;
        if (nd < n_nodes) {
            float v = acc[m] + bias;
            h[(size_t)nd * D + t] = v > 0.0f ? v : 0.0f;
        }
    }
}

// ---------------------------------------------------------------------------
extern "C" void kernel_launch(void* const* d_in, const int* in_sizes, int n_in,
                              void* d_out, int out_size, void* d_ws, size_t ws_size,
                              hipStream_t stream)
{
    const float* feature = (const float*)d_in[0];
    const int*   src     = (const int*)d_in[1];
    const int*   dst     = (const int*)d_in[2];
    const float* W       = (const float*)d_in[3];
    const float* b       = (const float*)d_in[4];
    float*       out     = (float*)d_out;

    const int E = in_sizes[1];
    const int N = in_sizes[0] / D;
    const int K = (N + BSIZE - 1) >> BSHIFT;        // buckets
    const int chunk = (E + NB_P - 1) / NB_P;

    // ---- workspace layout -------------------------------------------------
    size_t off = 0;
    auto alloc = [&](size_t bytes, size_t align) {
        off = (off + align - 1) / align * align;
        size_t r = off; off += bytes; return r;
    };
    size_t o_bh     = alloc((size_t)NB_P * K * 4, 16);
    size_t o_seg    = alloc((size_t)4 * K * 4, 16);
    size_t o_base   = alloc((size_t)(K + 1) * 4, 16);
    size_t o_gcur   = alloc((size_t)K * 4, 16);
    size_t o_packed = alloc((size_t)E * 4, 16);
    size_t o_wt     = alloc((size_t)D * D * 2, 16);
    size_t o_fbf    = alloc((size_t)N * D * 2, 16);
    size_t need_full = off;

    char* ws = (char*)d_ws;

    if (ws_size >= need_full && K <= KMAX) {
        int* blockHist = (int*)(ws + o_bh);
        int* segsum    = (int*)(ws + o_seg);
        int* base      = (int*)(ws + o_base);
        int* gcur      = (int*)(ws + o_gcur);
        int* csrPacked = (int*)(ws + o_packed);
        unsigned short* Wt  = (unsigned short*)(ws + o_wt);
        unsigned short* fbf = (unsigned short*)(ws + o_fbf);

        const long n8 = (long)N * D / 8;
        const int nConvF = (int)((n8 + 255) / 256);
        const int nConvW = (D * D / 4 + 255) / 256;

        prep_kernel<<<nConvF + nConvW + NB_P, 256, 0, stream>>>(
            feature, fbf, n8, W, Wt, dst, blockHist, E, K, chunk, nConvF, nConvW);
        {
            dim3 g((K + 255) / 256, 4);
            colsumA_kernel<<<g, 256, 0, stream>>>(blockHist, segsum, K);
        }
        basescan_kernel<<<1, 1024, 0, stream>>>(segsum, base, gcur, K);
        scatterB_kernel<<<NB_P, 256, 0, stream>>>(
            src, dst, blockHist, gcur, csrPacked, E, K, chunk);

        bucket_kernel<<<K, 256, 0, stream>>>(
            fbf, csrPacked, base, Wt, b, out, N);
    } else {
        hipMemsetAsync(d_out, 0, (size_t)out_size * sizeof(float), stream);
        scatter_kernel<<<(E + 3) / 4, 256, 0, stream>>>(feature, src, dst, out, E);
        linear_relu_kernel<<<(N + BM - 1) / BM, 256, 0, stream>>>(out, W, b, N);
    }
}